// Round 1
// baseline (1162.553 us; speedup 1.0000x reference)
//
#include <hip/hip_runtime.h>

// out = L@(X@W1 + X^2@W2) + X@W1 + b1 + b2
//   where L@ is the COO scatter: out[r] += vals[e] * Y[cols[e]]
// Kernel 1 (node_transform): Y = X@W1 + X^2@W2 (to ws), Z = X@W1 + b1 + b2 (to out)
// Kernel 2 (edge_scatter):   out[rows[e]] += vals[e] * Y[cols[e]]  (atomics)

__global__ __launch_bounds__(256) void node_transform(
    const float* __restrict__ X, const float* __restrict__ W1,
    const float* __restrict__ b1, const float* __restrict__ W2,
    const float* __restrict__ b2, float* __restrict__ Y,
    float* __restrict__ Z, int n_nodes)
{
    __shared__ float W1s[64 * 64];
    __shared__ float W2s[64 * 64];
    __shared__ float xs[64][65];   // +1 pad: rows i,4+i,8+i,12+i hit distinct banks
    __shared__ float bs[64];

    const int tid = threadIdx.x;
    const int base = blockIdx.x * 64;

    // Stage W1/W2 (4096 floats each) via float4: 256 threads x 4 iters
    {
        const float4* w1v = (const float4*)W1;
        const float4* w2v = (const float4*)W2;
        float4* s1 = (float4*)W1s;
        float4* s2 = (float4*)W2s;
#pragma unroll
        for (int i = 0; i < 4; ++i) {
            s1[tid + 256 * i] = w1v[tid + 256 * i];
            s2[tid + 256 * i] = w2v[tid + 256 * i];
        }
    }
    if (tid < 64) bs[tid] = b1[tid] + b2[tid];

    // Stage X tile: 64 contiguous rows x 64 floats = 4096 floats, coalesced float4
    {
#pragma unroll
        for (int i = 0; i < 4; ++i) {
            int idx = (tid + 256 * i) * 4;      // flat float index into the tile
            int r = idx >> 6, c = idx & 63;
            if (base + r < n_nodes) {
                float4 v = *(const float4*)(X + (size_t)base * 64 + idx);
                xs[r][c + 0] = v.x; xs[r][c + 1] = v.y;
                xs[r][c + 2] = v.z; xs[r][c + 3] = v.w;
            }
        }
    }
    __syncthreads();

    const int tx = tid & 15;   // feature group: features 4*tx .. 4*tx+3
    const int ty = tid >> 4;   // node group:    nodes    4*ty .. 4*ty+3

    float acc1[4][4] = {};
    float acc2[4][4] = {};

#pragma unroll 4
    for (int k = 0; k < 64; ++k) {
        float4 w1 = *(const float4*)(W1s + k * 64 + tx * 4);
        float4 w2 = *(const float4*)(W2s + k * 64 + tx * 4);
#pragma unroll
        for (int i = 0; i < 4; ++i) {
            float xv = xs[ty * 4 + i][k];
            float xq = xv * xv;
            acc1[i][0] = fmaf(xv, w1.x, acc1[i][0]);
            acc1[i][1] = fmaf(xv, w1.y, acc1[i][1]);
            acc1[i][2] = fmaf(xv, w1.z, acc1[i][2]);
            acc1[i][3] = fmaf(xv, w1.w, acc1[i][3]);
            acc2[i][0] = fmaf(xq, w2.x, acc2[i][0]);
            acc2[i][1] = fmaf(xq, w2.y, acc2[i][1]);
            acc2[i][2] = fmaf(xq, w2.z, acc2[i][2]);
            acc2[i][3] = fmaf(xq, w2.w, acc2[i][3]);
        }
    }

    float b0 = bs[tx * 4 + 0], bb1 = bs[tx * 4 + 1];
    float b2v = bs[tx * 4 + 2], b3 = bs[tx * 4 + 3];

#pragma unroll
    for (int i = 0; i < 4; ++i) {
        int node = base + ty * 4 + i;
        if (node < n_nodes) {
            float4 y, z;
            y.x = acc1[i][0] + acc2[i][0];
            y.y = acc1[i][1] + acc2[i][1];
            y.z = acc1[i][2] + acc2[i][2];
            y.w = acc1[i][3] + acc2[i][3];
            z.x = acc1[i][0] + b0;
            z.y = acc1[i][1] + bb1;
            z.z = acc1[i][2] + b2v;
            z.w = acc1[i][3] + b3;
            *(float4*)(Y + (size_t)node * 64 + tx * 4) = y;
            *(float4*)(Z + (size_t)node * 64 + tx * 4) = z;
        }
    }
}

__global__ __launch_bounds__(256) void edge_scatter(
    const int* __restrict__ rows, const int* __restrict__ cols,
    const float* __restrict__ vals, const float* __restrict__ Y,
    float* __restrict__ out, int n_edges)
{
    int t = blockIdx.x * 256 + threadIdx.x;
    int e = t >> 4;            // 16 threads per edge
    int f = (t & 15) << 2;     // each thread handles 4 features
    if (e >= n_edges) return;
    int r = rows[e];
    int c = cols[e];
    float v = vals[e];
    float4 y = *(const float4*)(Y + (size_t)c * 64 + f);
    float* o = out + (size_t)r * 64 + f;
    atomicAdd(o + 0, v * y.x);
    atomicAdd(o + 1, v * y.y);
    atomicAdd(o + 2, v * y.z);
    atomicAdd(o + 3, v * y.w);
}

extern "C" void kernel_launch(void* const* d_in, const int* in_sizes, int n_in,
                              void* d_out, int out_size, void* d_ws, size_t ws_size,
                              hipStream_t stream) {
    const int*   rows = (const int*)d_in[0];
    const int*   cols = (const int*)d_in[1];
    const float* vals = (const float*)d_in[2];
    const float* X    = (const float*)d_in[3];
    const float* W1   = (const float*)d_in[4];
    const float* b1   = (const float*)d_in[5];
    const float* W2   = (const float*)d_in[6];
    const float* b2   = (const float*)d_in[7];
    float* out = (float*)d_out;

    const int n_edges = in_sizes[0];
    const int n_nodes = in_sizes[3] / 64;

    float* Y = (float*)d_ws;   // n_nodes * 64 floats = 25.6 MB

    int nblocks = (n_nodes + 63) / 64;
    node_transform<<<nblocks, 256, 0, stream>>>(X, W1, b1, W2, b2, Y, out, n_nodes);

    long long threads = (long long)n_edges * 16;
    int eblocks = (int)((threads + 255) / 256);
    edge_scatter<<<eblocks, 256, 0, stream>>>(rows, cols, vals, Y, out, n_edges);
}

// Round 2
// 364.665 us; speedup vs baseline: 3.1880x; 3.1880x over previous
//
#include <hip/hip_runtime.h>

// out = L@(X@W1 + X^2@W2) + X@W1 + b1 + b2
// Y = X@W1 + X^2@W2 (ws), Z = X@W1 + b1 + b2 (written to out by node_transform)
// Then CSR-build (hist/scan/scatter) + per-node gather adds L@Y into out
// with zero output atomics.

__global__ __launch_bounds__(256) void node_transform(
    const float* __restrict__ X, const float* __restrict__ W1,
    const float* __restrict__ b1, const float* __restrict__ W2,
    const float* __restrict__ b2, float* __restrict__ Y,
    float* __restrict__ Z, int n_nodes)
{
    __shared__ float W1s[64 * 64];
    __shared__ float W2s[64 * 64];
    __shared__ float xs[64][65];
    __shared__ float bs[64];

    const int tid = threadIdx.x;
    const int base = blockIdx.x * 64;

    {
        const float4* w1v = (const float4*)W1;
        const float4* w2v = (const float4*)W2;
        float4* s1 = (float4*)W1s;
        float4* s2 = (float4*)W2s;
#pragma unroll
        for (int i = 0; i < 4; ++i) {
            s1[tid + 256 * i] = w1v[tid + 256 * i];
            s2[tid + 256 * i] = w2v[tid + 256 * i];
        }
    }
    if (tid < 64) bs[tid] = b1[tid] + b2[tid];

    {
#pragma unroll
        for (int i = 0; i < 4; ++i) {
            int idx = (tid + 256 * i) * 4;
            int r = idx >> 6, c = idx & 63;
            if (base + r < n_nodes) {
                float4 v = *(const float4*)(X + (size_t)base * 64 + idx);
                xs[r][c + 0] = v.x; xs[r][c + 1] = v.y;
                xs[r][c + 2] = v.z; xs[r][c + 3] = v.w;
            }
        }
    }
    __syncthreads();

    const int tx = tid & 15;
    const int ty = tid >> 4;

    float acc1[4][4] = {};
    float acc2[4][4] = {};

#pragma unroll 4
    for (int k = 0; k < 64; ++k) {
        float4 w1 = *(const float4*)(W1s + k * 64 + tx * 4);
        float4 w2 = *(const float4*)(W2s + k * 64 + tx * 4);
#pragma unroll
        for (int i = 0; i < 4; ++i) {
            float xv = xs[ty * 4 + i][k];
            float xq = xv * xv;
            acc1[i][0] = fmaf(xv, w1.x, acc1[i][0]);
            acc1[i][1] = fmaf(xv, w1.y, acc1[i][1]);
            acc1[i][2] = fmaf(xv, w1.z, acc1[i][2]);
            acc1[i][3] = fmaf(xv, w1.w, acc1[i][3]);
            acc2[i][0] = fmaf(xq, w2.x, acc2[i][0]);
            acc2[i][1] = fmaf(xq, w2.y, acc2[i][1]);
            acc2[i][2] = fmaf(xq, w2.z, acc2[i][2]);
            acc2[i][3] = fmaf(xq, w2.w, acc2[i][3]);
        }
    }

    float b0 = bs[tx * 4 + 0], bb1 = bs[tx * 4 + 1];
    float b2v = bs[tx * 4 + 2], b3 = bs[tx * 4 + 3];

#pragma unroll
    for (int i = 0; i < 4; ++i) {
        int node = base + ty * 4 + i;
        if (node < n_nodes) {
            float4 y, z;
            y.x = acc1[i][0] + acc2[i][0];
            y.y = acc1[i][1] + acc2[i][1];
            y.z = acc1[i][2] + acc2[i][2];
            y.w = acc1[i][3] + acc2[i][3];
            z.x = acc1[i][0] + b0;
            z.y = acc1[i][1] + bb1;
            z.z = acc1[i][2] + b2v;
            z.w = acc1[i][3] + b3;
            *(float4*)(Y + (size_t)node * 64 + tx * 4) = y;
            *(float4*)(Z + (size_t)node * 64 + tx * 4) = z;
        }
    }
}

// ---------------- CSR build ----------------

__global__ __launch_bounds__(256) void zero_counts(int* __restrict__ c, int n) {
    int i = blockIdx.x * 256 + threadIdx.x;
    if (i < n) c[i] = 0;
}

__global__ __launch_bounds__(256) void hist_rows(
    const int* __restrict__ rows, int* __restrict__ counts, int n_edges) {
    int e = blockIdx.x * 256 + threadIdx.x;
    if (e < n_edges) atomicAdd(&counts[rows[e]], 1);
}

// exclusive scan of counts within each 256-block; block totals to bsum
__global__ __launch_bounds__(256) void scan1(
    const int* __restrict__ counts, int* __restrict__ start,
    int* __restrict__ bsum, int n) {
    __shared__ int s[256];
    int i = blockIdx.x * 256 + threadIdx.x;
    int v = (i < n) ? counts[i] : 0;
    s[threadIdx.x] = v;
    __syncthreads();
#pragma unroll
    for (int o = 1; o < 256; o <<= 1) {
        int t = (threadIdx.x >= o) ? s[threadIdx.x - o] : 0;
        __syncthreads();
        s[threadIdx.x] += t;
        __syncthreads();
    }
    if (i < n) start[i] = s[threadIdx.x] - v;   // exclusive
    if (threadIdx.x == 255) bsum[blockIdx.x] = s[255];
}

// exclusive scan of up to 512 block sums (NB=391 here), single block
__global__ __launch_bounds__(512) void scan2(
    const int* __restrict__ bsum, int* __restrict__ boff, int nb) {
    __shared__ int s[512];
    int i = threadIdx.x;
    int v = (i < nb) ? bsum[i] : 0;
    s[i] = v;
    __syncthreads();
#pragma unroll
    for (int o = 1; o < 512; o <<= 1) {
        int t = (i >= o) ? s[i - o] : 0;
        __syncthreads();
        s[i] += t;
        __syncthreads();
    }
    if (i < nb) boff[i] = s[i] - v;
}

// add block offsets; init cursor = start
__global__ __launch_bounds__(256) void scan3(
    int* __restrict__ start, const int* __restrict__ boff,
    int* __restrict__ cursor, int n) {
    int i = blockIdx.x * 256 + threadIdx.x;
    if (i >= n) return;
    int sg = start[i] + boff[blockIdx.x];
    start[i] = sg;
    cursor[i] = sg;
}

__global__ __launch_bounds__(256) void scatter_edges(
    const int* __restrict__ rows, const int* __restrict__ cols,
    const float* __restrict__ vals, int* __restrict__ cursor,
    int2* __restrict__ packed, int n_edges) {
    int e = blockIdx.x * 256 + threadIdx.x;
    if (e >= n_edges) return;
    int r = rows[e];
    int p = atomicAdd(&cursor[r], 1);
    packed[p] = make_int2(cols[e], __float_as_int(vals[e]));
}

// one wave per node, one lane per feature; no output atomics
// after scatter, cursor[r] == row end (start[r] + count[r])
__global__ __launch_bounds__(256) void gather_rows(
    const int* __restrict__ start, const int* __restrict__ cursor,
    const int2* __restrict__ packed, const float* __restrict__ Y,
    float* __restrict__ out, int n_nodes) {
    int node = blockIdx.x * 4 + (threadIdx.x >> 6);
    int f = threadIdx.x & 63;
    if (node >= n_nodes) return;
    int s = start[node];
    int e = cursor[node];
    float acc0 = 0.f, acc1 = 0.f;
    int i = s;
    for (; i + 1 < e; i += 2) {
        int2 a = packed[i];
        int2 b = packed[i + 1];
        acc0 = fmaf(__int_as_float(a.y), Y[(size_t)a.x * 64 + f], acc0);
        acc1 = fmaf(__int_as_float(b.y), Y[(size_t)b.x * 64 + f], acc1);
    }
    if (i < e) {
        int2 a = packed[i];
        acc0 = fmaf(__int_as_float(a.y), Y[(size_t)a.x * 64 + f], acc0);
    }
    size_t o = (size_t)node * 64 + f;
    out[o] += acc0 + acc1;   // out holds Z from node_transform
}

// ---------------- fallback (round-1 atomic path) ----------------

__global__ __launch_bounds__(256) void edge_scatter(
    const int* __restrict__ rows, const int* __restrict__ cols,
    const float* __restrict__ vals, const float* __restrict__ Y,
    float* __restrict__ out, int n_edges)
{
    int t = blockIdx.x * 256 + threadIdx.x;
    int e = t >> 4;
    int f = (t & 15) << 2;
    if (e >= n_edges) return;
    int r = rows[e];
    int c = cols[e];
    float v = vals[e];
    float4 y = *(const float4*)(Y + (size_t)c * 64 + f);
    float* o = out + (size_t)r * 64 + f;
    atomicAdd(o + 0, v * y.x);
    atomicAdd(o + 1, v * y.y);
    atomicAdd(o + 2, v * y.z);
    atomicAdd(o + 3, v * y.w);
}

extern "C" void kernel_launch(void* const* d_in, const int* in_sizes, int n_in,
                              void* d_out, int out_size, void* d_ws, size_t ws_size,
                              hipStream_t stream) {
    const int*   rows = (const int*)d_in[0];
    const int*   cols = (const int*)d_in[1];
    const float* vals = (const float*)d_in[2];
    const float* X    = (const float*)d_in[3];
    const float* W1   = (const float*)d_in[4];
    const float* b1   = (const float*)d_in[5];
    const float* W2   = (const float*)d_in[6];
    const float* b2   = (const float*)d_in[7];
    float* out = (float*)d_out;

    const int n_edges = in_sizes[0];
    const int n_nodes = in_sizes[3] / 64;
    const int NB = (n_nodes + 255) / 256;   // 391 for N=100000

    // workspace layout
    char* ws = (char*)d_ws;
    size_t o_Y      = 0;
    size_t o_counts = o_Y + (size_t)n_nodes * 64 * 4;
    size_t o_start  = o_counts + (size_t)n_nodes * 4;
    size_t o_cursor = o_start + (size_t)n_nodes * 4;
    size_t o_bsum   = o_cursor + (size_t)n_nodes * 4;
    size_t o_boff   = o_bsum + 4096;
    size_t o_packed = o_boff + 4096;
    size_t need     = o_packed + (size_t)n_edges * 8;

    float* Y = (float*)(ws + o_Y);

    int nblocks = (n_nodes + 63) / 64;
    node_transform<<<nblocks, 256, 0, stream>>>(X, W1, b1, W2, b2, Y, out, n_nodes);

    if (ws_size >= need && NB <= 512) {
        int*  counts = (int*)(ws + o_counts);
        int*  start  = (int*)(ws + o_start);
        int*  cursor = (int*)(ws + o_cursor);
        int*  bsum   = (int*)(ws + o_bsum);
        int*  boff   = (int*)(ws + o_boff);
        int2* packed = (int2*)(ws + o_packed);

        int nb_nodes = (n_nodes + 255) / 256;
        int nb_edges = (n_edges + 255) / 256;

        zero_counts<<<nb_nodes, 256, 0, stream>>>(counts, n_nodes);
        hist_rows<<<nb_edges, 256, 0, stream>>>(rows, counts, n_edges);
        scan1<<<NB, 256, 0, stream>>>(counts, start, bsum, n_nodes);
        scan2<<<1, 512, 0, stream>>>(bsum, boff, NB);
        scan3<<<NB, 256, 0, stream>>>(start, boff, cursor, n_nodes);
        scatter_edges<<<nb_edges, 256, 0, stream>>>(rows, cols, vals, cursor, packed, n_edges);
        gather_rows<<<(n_nodes + 3) / 4, 256, 0, stream>>>(start, cursor, packed, Y, out, n_nodes);
    } else {
        long long threads = (long long)n_edges * 16;
        int eblocks = (int)((threads + 255) / 256);
        edge_scatter<<<eblocks, 256, 0, stream>>>(rows, cols, vals, Y, out, n_edges);
    }
}

// Round 3
// 314.303 us; speedup vs baseline: 3.6988x; 1.1602x over previous
//
#include <hip/hip_runtime.h>

// out = L@(X@W1 + X^2@W2) + X@W1 + b1 + b2
// Y = X@W1 + X^2@W2 (ws), Z = X@W1 + b1 + b2 (written to out by node_transform)
// CSR build (hist/scan/scatter) + per-node wave gather, no output atomics.

__global__ __launch_bounds__(256) void node_transform(
    const float* __restrict__ X, const float* __restrict__ W1,
    const float* __restrict__ b1, const float* __restrict__ W2,
    const float* __restrict__ b2, float* __restrict__ Y,
    float* __restrict__ Z, int n_nodes)
{
    __shared__ float W1s[64 * 64];
    __shared__ float W2s[64 * 64];
    __shared__ float xs[128][65];
    __shared__ float bs[64];

    const int tid = threadIdx.x;
    const int base = blockIdx.x * 128;

    // Stage W1/W2 (4096 floats each) via float4
    {
        const float4* w1v = (const float4*)W1;
        const float4* w2v = (const float4*)W2;
        float4* s1 = (float4*)W1s;
        float4* s2 = (float4*)W2s;
#pragma unroll
        for (int i = 0; i < 4; ++i) {
            s1[tid + 256 * i] = w1v[tid + 256 * i];
            s2[tid + 256 * i] = w2v[tid + 256 * i];
        }
    }
    if (tid < 64) bs[tid] = b1[tid] + b2[tid];

    // Stage X tile: 128 rows x 64 floats = 8192 floats, coalesced float4
    {
#pragma unroll
        for (int i = 0; i < 8; ++i) {
            int idx = (tid + 256 * i) * 4;
            int r = idx >> 6, c = idx & 63;
            if (base + r < n_nodes) {
                float4 v = *(const float4*)(X + (size_t)base * 64 + idx);
                xs[r][c + 0] = v.x; xs[r][c + 1] = v.y;
                xs[r][c + 2] = v.z; xs[r][c + 3] = v.w;
            }
        }
    }
    __syncthreads();

    const int tx = tid & 7;    // features 8*tx .. 8*tx+7
    const int ty = tid >> 3;   // nodes 4*ty .. 4*ty+3   (ty 0..31)

    float acc1[4][8] = {};
    float acc2[4][8] = {};

#pragma unroll 2
    for (int k = 0; k < 64; ++k) {
        float4 wa0 = *(const float4*)(W1s + k * 64 + tx * 8);
        float4 wa1 = *(const float4*)(W1s + k * 64 + tx * 8 + 4);
        float4 wb0 = *(const float4*)(W2s + k * 64 + tx * 8);
        float4 wb1 = *(const float4*)(W2s + k * 64 + tx * 8 + 4);
#pragma unroll
        for (int i = 0; i < 4; ++i) {
            float xv = xs[ty * 4 + i][k];
            float xq = xv * xv;
            acc1[i][0] = fmaf(xv, wa0.x, acc1[i][0]);
            acc1[i][1] = fmaf(xv, wa0.y, acc1[i][1]);
            acc1[i][2] = fmaf(xv, wa0.z, acc1[i][2]);
            acc1[i][3] = fmaf(xv, wa0.w, acc1[i][3]);
            acc1[i][4] = fmaf(xv, wa1.x, acc1[i][4]);
            acc1[i][5] = fmaf(xv, wa1.y, acc1[i][5]);
            acc1[i][6] = fmaf(xv, wa1.z, acc1[i][6]);
            acc1[i][7] = fmaf(xv, wa1.w, acc1[i][7]);
            acc2[i][0] = fmaf(xq, wb0.x, acc2[i][0]);
            acc2[i][1] = fmaf(xq, wb0.y, acc2[i][1]);
            acc2[i][2] = fmaf(xq, wb0.z, acc2[i][2]);
            acc2[i][3] = fmaf(xq, wb0.w, acc2[i][3]);
            acc2[i][4] = fmaf(xq, wb1.x, acc2[i][4]);
            acc2[i][5] = fmaf(xq, wb1.y, acc2[i][5]);
            acc2[i][6] = fmaf(xq, wb1.z, acc2[i][6]);
            acc2[i][7] = fmaf(xq, wb1.w, acc2[i][7]);
        }
    }

    float bv[8];
#pragma unroll
    for (int j = 0; j < 8; ++j) bv[j] = bs[tx * 8 + j];

#pragma unroll
    for (int i = 0; i < 4; ++i) {
        int node = base + ty * 4 + i;
        if (node < n_nodes) {
            float y[8], z[8];
#pragma unroll
            for (int j = 0; j < 8; ++j) {
                y[j] = acc1[i][j] + acc2[i][j];
                z[j] = acc1[i][j] + bv[j];
            }
            float* yp = Y + (size_t)node * 64 + tx * 8;
            float* zp = Z + (size_t)node * 64 + tx * 8;
            *(float4*)(yp)     = make_float4(y[0], y[1], y[2], y[3]);
            *(float4*)(yp + 4) = make_float4(y[4], y[5], y[6], y[7]);
            *(float4*)(zp)     = make_float4(z[0], z[1], z[2], z[3]);
            *(float4*)(zp + 4) = make_float4(z[4], z[5], z[6], z[7]);
        }
    }
}

// ---------------- CSR build ----------------

__global__ __launch_bounds__(256) void zero_counts(int* __restrict__ c, int n) {
    int i = blockIdx.x * 256 + threadIdx.x;
    if (i < n) c[i] = 0;
}

__global__ __launch_bounds__(256) void hist_rows(
    const int* __restrict__ rows, int* __restrict__ counts, int n_edges) {
    int e = blockIdx.x * 256 + threadIdx.x;
    if (e < n_edges) atomicAdd(&counts[rows[e]], 1);
}

__global__ __launch_bounds__(256) void scan1(
    const int* __restrict__ counts, int* __restrict__ start,
    int* __restrict__ bsum, int n) {
    __shared__ int s[256];
    int i = blockIdx.x * 256 + threadIdx.x;
    int v = (i < n) ? counts[i] : 0;
    s[threadIdx.x] = v;
    __syncthreads();
#pragma unroll
    for (int o = 1; o < 256; o <<= 1) {
        int t = (threadIdx.x >= o) ? s[threadIdx.x - o] : 0;
        __syncthreads();
        s[threadIdx.x] += t;
        __syncthreads();
    }
    if (i < n) start[i] = s[threadIdx.x] - v;
    if (threadIdx.x == 255) bsum[blockIdx.x] = s[255];
}

__global__ __launch_bounds__(512) void scan2(
    const int* __restrict__ bsum, int* __restrict__ boff, int nb) {
    __shared__ int s[512];
    int i = threadIdx.x;
    int v = (i < nb) ? bsum[i] : 0;
    s[i] = v;
    __syncthreads();
#pragma unroll
    for (int o = 1; o < 512; o <<= 1) {
        int t = (i >= o) ? s[i - o] : 0;
        __syncthreads();
        s[i] += t;
        __syncthreads();
    }
    if (i < nb) boff[i] = s[i] - v;
}

__global__ __launch_bounds__(256) void scan3(
    int* __restrict__ start, const int* __restrict__ boff,
    int* __restrict__ cursor, int n) {
    int i = blockIdx.x * 256 + threadIdx.x;
    if (i >= n) return;
    int sg = start[i] + boff[blockIdx.x];
    start[i] = sg;
    cursor[i] = sg;
}

__global__ __launch_bounds__(256) void scatter_edges(
    const int* __restrict__ rows, const int* __restrict__ cols,
    const float* __restrict__ vals, int* __restrict__ cursor,
    int2* __restrict__ packed, int n_edges) {
    int e = blockIdx.x * 256 + threadIdx.x;
    if (e >= n_edges) return;
    int r = rows[e];
    int p = atomicAdd(&cursor[r], 1);
    packed[p] = make_int2(cols[e], __float_as_int(vals[e]));
}

// one wave per node, lane = feature. Whole row's edges loaded in ONE
// coalesced 512B load, then shfl-broadcast -> independent Y loads (MLP).
__global__ __launch_bounds__(256) void gather_rows(
    const int* __restrict__ start, const int* __restrict__ cursor,
    const int2* __restrict__ packed, const float* __restrict__ Y,
    float* __restrict__ out, int n_nodes) {
    int wave = threadIdx.x >> 6;
    int lane = threadIdx.x & 63;
    int node = blockIdx.x * 4 + wave;
    if (node >= n_nodes) return;
    int s = start[node];
    int e = cursor[node];
    float acc = 0.f;
    for (int b = s; b < e; b += 64) {
        int cnt = min(64, e - b);
        int pc = 0; float pv = 0.f;
        if (lane < cnt) {
            int2 a = packed[b + lane];
            pc = a.x;
            pv = __int_as_float(a.y);
        }
        int j = 0;
        for (; j + 4 <= cnt; j += 4) {
            int   c0 = __shfl(pc, j),     c1 = __shfl(pc, j + 1);
            int   c2 = __shfl(pc, j + 2), c3 = __shfl(pc, j + 3);
            float v0 = __shfl(pv, j),     v1 = __shfl(pv, j + 1);
            float v2 = __shfl(pv, j + 2), v3 = __shfl(pv, j + 3);
            float y0 = Y[(size_t)c0 * 64 + lane];
            float y1 = Y[(size_t)c1 * 64 + lane];
            float y2 = Y[(size_t)c2 * 64 + lane];
            float y3 = Y[(size_t)c3 * 64 + lane];
            acc = fmaf(v0, y0, acc);
            acc = fmaf(v1, y1, acc);
            acc = fmaf(v2, y2, acc);
            acc = fmaf(v3, y3, acc);
        }
        for (; j < cnt; ++j) {
            int   c0 = __shfl(pc, j);
            float v0 = __shfl(pv, j);
            acc = fmaf(v0, Y[(size_t)c0 * 64 + lane], acc);
        }
    }
    size_t o = (size_t)node * 64 + lane;
    out[o] += acc;   // out holds Z from node_transform
}

// ---------------- fallback (atomic path) ----------------

__global__ __launch_bounds__(256) void edge_scatter(
    const int* __restrict__ rows, const int* __restrict__ cols,
    const float* __restrict__ vals, const float* __restrict__ Y,
    float* __restrict__ out, int n_edges)
{
    int t = blockIdx.x * 256 + threadIdx.x;
    int e = t >> 4;
    int f = (t & 15) << 2;
    if (e >= n_edges) return;
    int r = rows[e];
    int c = cols[e];
    float v = vals[e];
    float4 y = *(const float4*)(Y + (size_t)c * 64 + f);
    float* o = out + (size_t)r * 64 + f;
    atomicAdd(o + 0, v * y.x);
    atomicAdd(o + 1, v * y.y);
    atomicAdd(o + 2, v * y.z);
    atomicAdd(o + 3, v * y.w);
}

extern "C" void kernel_launch(void* const* d_in, const int* in_sizes, int n_in,
                              void* d_out, int out_size, void* d_ws, size_t ws_size,
                              hipStream_t stream) {
    const int*   rows = (const int*)d_in[0];
    const int*   cols = (const int*)d_in[1];
    const float* vals = (const float*)d_in[2];
    const float* X    = (const float*)d_in[3];
    const float* W1   = (const float*)d_in[4];
    const float* b1   = (const float*)d_in[5];
    const float* W2   = (const float*)d_in[6];
    const float* b2   = (const float*)d_in[7];
    float* out = (float*)d_out;

    const int n_edges = in_sizes[0];
    const int n_nodes = in_sizes[3] / 64;
    const int NB = (n_nodes + 255) / 256;

    char* ws = (char*)d_ws;
    size_t o_Y      = 0;
    size_t o_counts = o_Y + (size_t)n_nodes * 64 * 4;
    size_t o_start  = o_counts + (size_t)n_nodes * 4;
    size_t o_cursor = o_start + (size_t)n_nodes * 4;
    size_t o_bsum   = o_cursor + (size_t)n_nodes * 4;
    size_t o_boff   = o_bsum + 4096;
    size_t o_packed = o_boff + 4096;
    size_t need     = o_packed + (size_t)n_edges * 8;

    float* Y = (float*)(ws + o_Y);

    int nblocks = (n_nodes + 127) / 128;
    node_transform<<<nblocks, 256, 0, stream>>>(X, W1, b1, W2, b2, Y, out, n_nodes);

    if (ws_size >= need && NB <= 512) {
        int*  counts = (int*)(ws + o_counts);
        int*  start  = (int*)(ws + o_start);
        int*  cursor = (int*)(ws + o_cursor);
        int*  bsum   = (int*)(ws + o_bsum);
        int*  boff   = (int*)(ws + o_boff);
        int2* packed = (int2*)(ws + o_packed);

        int nb_nodes = (n_nodes + 255) / 256;
        int nb_edges = (n_edges + 255) / 256;

        zero_counts<<<nb_nodes, 256, 0, stream>>>(counts, n_nodes);
        hist_rows<<<nb_edges, 256, 0, stream>>>(rows, counts, n_edges);
        scan1<<<NB, 256, 0, stream>>>(counts, start, bsum, n_nodes);
        scan2<<<1, 512, 0, stream>>>(bsum, boff, NB);
        scan3<<<NB, 256, 0, stream>>>(start, boff, cursor, n_nodes);
        scatter_edges<<<nb_edges, 256, 0, stream>>>(rows, cols, vals, cursor, packed, n_edges);
        gather_rows<<<(n_nodes + 3) / 4, 256, 0, stream>>>(start, cursor, packed, Y, out, n_nodes);
    } else {
        long long threads = (long long)n_edges * 16;
        int eblocks = (int)((threads + 255) / 256);
        edge_scatter<<<eblocks, 256, 0, stream>>>(rows, cols, vals, Y, out, n_edges);
    }
}